// Round 1
// baseline (2287.893 us; speedup 1.0000x reference)
//
#include <hip/hip_runtime.h>
#include <math.h>

#define H 1024
#define SEQ 2048
#define NHEADS 16
#define HSZ 64
#define NROWS 8192            // B*S = 4*2048
constexpr float SCALE = 0.125f;  // 1/sqrt(64)

// ---------------------------------------------------------------------------
// Tiled fp32 GEMM: Y[n,o] = sum_h X[n,h] * W[o,h] + bias[o]
// Tile 128x128, BK=16, 256 threads, 8x8 micro-tile.
// LDS tiles stored k-major ([k][row]) so inner-loop reads are same-row
// (broadcast on A side, 2-way-free on B side).
// SCATTER=true writes Y to [B, NH, S, HS] layout, else row-major [N, H].
// ---------------------------------------------------------------------------
template <bool SCATTER>
__device__ __forceinline__ void gemm_body(const float* __restrict__ X,
                                          const float* __restrict__ W,
                                          const float* __restrict__ bias,
                                          float* __restrict__ Y) {
  __shared__ float As[16][132];  // [k][row], pad +4
  __shared__ float Bs[16][132];  // [k][col]

  const int t = threadIdx.x;
  const int tx = t & 15;   // 0..15 -> cols
  const int ty = t >> 4;   // 0..15 -> rows
  const int row0 = blockIdx.y * 128;
  const int col0 = blockIdx.x * 128;

  float acc[8][8];
#pragma unroll
  for (int i = 0; i < 8; ++i)
#pragma unroll
    for (int j = 0; j < 8; ++j) acc[i][j] = 0.0f;

  const int sr = t >> 2;         // 0..63 (staging row)
  const int sk = (t & 3) << 2;   // 0,4,8,12 (staging k)

  for (int k0 = 0; k0 < H; k0 += 16) {
#pragma unroll
    for (int p = 0; p < 2; ++p) {
      const int r = sr + 64 * p;
      float4 xa = *(const float4*)&X[(size_t)(row0 + r) * H + k0 + sk];
      As[sk + 0][r] = xa.x;
      As[sk + 1][r] = xa.y;
      As[sk + 2][r] = xa.z;
      As[sk + 3][r] = xa.w;
      float4 wb = *(const float4*)&W[(size_t)(col0 + r) * H + k0 + sk];
      Bs[sk + 0][r] = wb.x;
      Bs[sk + 1][r] = wb.y;
      Bs[sk + 2][r] = wb.z;
      Bs[sk + 3][r] = wb.w;
    }
    __syncthreads();
#pragma unroll
    for (int k = 0; k < 16; ++k) {
      float4 a0 = *(const float4*)&As[k][ty * 4];
      float4 a1 = *(const float4*)&As[k][ty * 4 + 64];
      float4 b0 = *(const float4*)&Bs[k][tx * 4];
      float4 b1 = *(const float4*)&Bs[k][tx * 4 + 64];
      float a[8] = {a0.x, a0.y, a0.z, a0.w, a1.x, a1.y, a1.z, a1.w};
      float b[8] = {b0.x, b0.y, b0.z, b0.w, b1.x, b1.y, b1.z, b1.w};
#pragma unroll
      for (int i = 0; i < 8; ++i)
#pragma unroll
        for (int j = 0; j < 8; ++j) acc[i][j] += a[i] * b[j];
    }
    __syncthreads();
  }

  // epilogue: bias + store
#pragma unroll
  for (int i = 0; i < 8; ++i) {
    const int r = row0 + ty * 4 + (i & 3) + (i >> 2) * 64;
#pragma unroll
    for (int jg = 0; jg < 2; ++jg) {
      const int c = col0 + tx * 4 + jg * 64;
      float4 bb = *(const float4*)&bias[c];
      float4 v;
      v.x = acc[i][jg * 4 + 0] + bb.x;
      v.y = acc[i][jg * 4 + 1] + bb.y;
      v.z = acc[i][jg * 4 + 2] + bb.z;
      v.w = acc[i][jg * 4 + 3] + bb.w;
      if (SCATTER) {
        const int b = r / SEQ, s = r % SEQ;
        const int head = c / HSZ, hs = c % HSZ;
        *(float4*)&Y[(((size_t)(b * NHEADS + head) * SEQ + s) * HSZ) + hs] = v;
      } else {
        *(float4*)&Y[(size_t)r * H + c] = v;
      }
    }
  }
}

__global__ __launch_bounds__(256) void qkv_gemm(
    const float* __restrict__ X, const float* __restrict__ Wq,
    const float* __restrict__ bq, const float* __restrict__ Wk,
    const float* __restrict__ bk, const float* __restrict__ Wv,
    const float* __restrict__ bv, float* __restrict__ Qo,
    float* __restrict__ Ko, float* __restrict__ Vo) {
  const float* W;
  const float* bias;
  float* Y;
  if (blockIdx.z == 0) {
    W = Wq; bias = bq; Y = Qo;
  } else if (blockIdx.z == 1) {
    W = Wk; bias = bk; Y = Ko;
  } else {
    W = Wv; bias = bv; Y = Vo;
  }
  gemm_body<true>(X, W, bias, Y);
}

__global__ __launch_bounds__(256) void out_gemm(const float* __restrict__ X,
                                                const float* __restrict__ W,
                                                const float* __restrict__ bias,
                                                float* __restrict__ Y) {
  gemm_body<false>(X, W, bias, Y);
}

// ---------------------------------------------------------------------------
// Flash-style attention, fp32. One block per (qtile=64 rows, head, batch).
// 256 threads: tx = t&15 (key/col group), ty = t>>4 (query/row group).
// Thread owns S[q=ty+16i][k=tx+16j] (4x4) so per-row reduce is a 16-lane
// shfl_xor. P round-trips through LDS for the PV product.
// ---------------------------------------------------------------------------
__global__ __launch_bounds__(256) void attn_kernel(const float* __restrict__ Q,
                                                   const float* __restrict__ K,
                                                   const float* __restrict__ V,
                                                   float* __restrict__ CTX) {
  __shared__ float Qs[64][68];
  __shared__ float Ks[64][68];
  __shared__ float Vs[64][68];
  __shared__ float Ps[64][68];

  const int t = threadIdx.x;
  const int tx = t & 15;
  const int ty = t >> 4;
  const int qt = blockIdx.x;
  const int h = blockIdx.y;
  const int b = blockIdx.z;

  const size_t base = ((size_t)(b * NHEADS + h)) * SEQ * HSZ;
  const float* Qg = Q + base + (size_t)qt * 64 * HSZ;
  const float* Kg = K + base;
  const float* Vg = V + base;

  const int sr = t >> 4;        // 0..15 staging row (with 4 passes)
  const int sc = (t & 15) * 4;  // 0..60 staging col

  // stage Q tile, pre-scaled
#pragma unroll
  for (int p = 0; p < 4; ++p) {
    const int r = sr + p * 16;
    float4 v = *(const float4*)&Qg[(size_t)r * HSZ + sc];
    Qs[r][sc + 0] = v.x * SCALE;
    Qs[r][sc + 1] = v.y * SCALE;
    Qs[r][sc + 2] = v.z * SCALE;
    Qs[r][sc + 3] = v.w * SCALE;
  }

  float m[4], l[4];
  float4 O[4];
#pragma unroll
  for (int i = 0; i < 4; ++i) {
    m[i] = -INFINITY;
    l[i] = 0.0f;
    O[i] = make_float4(0.f, 0.f, 0.f, 0.f);
  }

  for (int kt = 0; kt < SEQ / 64; ++kt) {
    __syncthreads();  // prev PV done (and Q staged on first iter)
    // stage K, V tile
#pragma unroll
    for (int p = 0; p < 4; ++p) {
      const int r = sr + p * 16;
      float4 kv = *(const float4*)&Kg[(size_t)(kt * 64 + r) * HSZ + sc];
      Ks[r][sc + 0] = kv.x;
      Ks[r][sc + 1] = kv.y;
      Ks[r][sc + 2] = kv.z;
      Ks[r][sc + 3] = kv.w;
      float4 vv = *(const float4*)&Vg[(size_t)(kt * 64 + r) * HSZ + sc];
      Vs[r][sc + 0] = vv.x;
      Vs[r][sc + 1] = vv.y;
      Vs[r][sc + 2] = vv.z;
      Vs[r][sc + 3] = vv.w;
    }
    __syncthreads();

    // scores: S[i][j] = dot(Qrow, Krow) (Q pre-scaled)
    float S[4][4];
#pragma unroll
    for (int i = 0; i < 4; ++i)
#pragma unroll
      for (int j = 0; j < 4; ++j) S[i][j] = 0.0f;

#pragma unroll 4
    for (int d0 = 0; d0 < 16; ++d0) {
      float4 qv[4];
#pragma unroll
      for (int i = 0; i < 4; ++i)
        qv[i] = *(const float4*)&Qs[ty + 16 * i][d0 * 4];
#pragma unroll
      for (int j = 0; j < 4; ++j) {
        float4 kv4 = *(const float4*)&Ks[tx + 16 * j][d0 * 4];
#pragma unroll
        for (int i = 0; i < 4; ++i) {
          S[i][j] += qv[i].x * kv4.x + qv[i].y * kv4.y + qv[i].z * kv4.z +
                     qv[i].w * kv4.w;
        }
      }
    }

    // online softmax update (row = 16 tx lanes share via shfl_xor)
#pragma unroll
    for (int i = 0; i < 4; ++i) {
      float rm = fmaxf(fmaxf(S[i][0], S[i][1]), fmaxf(S[i][2], S[i][3]));
      rm = fmaxf(rm, __shfl_xor(rm, 1));
      rm = fmaxf(rm, __shfl_xor(rm, 2));
      rm = fmaxf(rm, __shfl_xor(rm, 4));
      rm = fmaxf(rm, __shfl_xor(rm, 8));
      const float mn = fmaxf(m[i], rm);
      const float alpha = __expf(m[i] - mn);
      m[i] = mn;
      float rs = 0.0f;
#pragma unroll
      for (int j = 0; j < 4; ++j) {
        const float p = __expf(S[i][j] - mn);
        S[i][j] = p;
        rs += p;
      }
      rs += __shfl_xor(rs, 1);
      rs += __shfl_xor(rs, 2);
      rs += __shfl_xor(rs, 4);
      rs += __shfl_xor(rs, 8);
      l[i] = l[i] * alpha + rs;
      O[i].x *= alpha;
      O[i].y *= alpha;
      O[i].z *= alpha;
      O[i].w *= alpha;
    }

    // publish P
#pragma unroll
    for (int i = 0; i < 4; ++i)
#pragma unroll
      for (int j = 0; j < 4; ++j) Ps[ty + 16 * i][tx + 16 * j] = S[i][j];
    __syncthreads();

    // PV: O[q][d] += sum_k P[q][k] * V[k][d];  thread owns d = tx*4..+3
#pragma unroll 4
    for (int k0 = 0; k0 < 16; ++k0) {
      float4 pv[4];
#pragma unroll
      for (int i = 0; i < 4; ++i)
        pv[i] = *(const float4*)&Ps[ty + 16 * i][k0 * 4];
#pragma unroll
      for (int j2 = 0; j2 < 4; ++j2) {
        float4 v4 = *(const float4*)&Vs[k0 * 4 + j2][tx * 4];
#pragma unroll
        for (int i = 0; i < 4; ++i) {
          const float* pf = (const float*)&pv[i];
          const float p = pf[j2];
          O[i].x += p * v4.x;
          O[i].y += p * v4.y;
          O[i].z += p * v4.z;
          O[i].w += p * v4.w;
        }
      }
    }
  }

  // epilogue: normalize, write ctx in concat layout [B, S, H]
#pragma unroll
  for (int i = 0; i < 4; ++i) {
    const float inv = 1.0f / l[i];
    const int s = qt * 64 + ty + 16 * i;
    float4 o;
    o.x = O[i].x * inv;
    o.y = O[i].y * inv;
    o.z = O[i].z * inv;
    o.w = O[i].w * inv;
    *(float4*)&CTX[((size_t)(b * SEQ + s)) * H + h * HSZ + tx * 4] = o;
  }
}

// ---------------------------------------------------------------------------
extern "C" void kernel_launch(void* const* d_in, const int* in_sizes, int n_in,
                              void* d_out, int out_size, void* d_ws,
                              size_t ws_size, hipStream_t stream) {
  const float* x = (const float*)d_in[0];
  const float* Wq = (const float*)d_in[1];
  const float* bq = (const float*)d_in[2];
  const float* Wk = (const float*)d_in[3];
  const float* bk = (const float*)d_in[4];
  const float* Wv = (const float*)d_in[5];
  const float* bv = (const float*)d_in[6];
  const float* Wo = (const float*)d_in[7];
  const float* bo = (const float*)d_in[8];

  const size_t PER = (size_t)4 * NHEADS * SEQ * HSZ;  // 8388608 elems
  float* Qb = (float*)d_ws;
  float* Kb = Qb + PER;
  float* Vb = Kb + PER;
  float* CTX = Vb + PER;

  // QKV projections: [8192,1024] x [1024,1024]^T -> scatter to [B,NH,S,HS]
  qkv_gemm<<<dim3(H / 128, NROWS / 128, 3), 256, 0, stream>>>(
      x, Wq, bq, Wk, bk, Wv, bv, Qb, Kb, Vb);

  // attention: one block per (qtile, head, batch)
  attn_kernel<<<dim3(SEQ / 64, NHEADS, 4), 256, 0, stream>>>(Qb, Kb, Vb, CTX);

  // output projection: plain row-major into d_out
  out_gemm<<<dim3(H / 128, NROWS / 128), 256, 0, stream>>>(CTX, Wo, bo,
                                                           (float*)d_out);
}

// Round 3
// 1009.806 us; speedup vs baseline: 2.2657x; 2.2657x over previous
//
#include <hip/hip_runtime.h>
#include <math.h>

#define H 1024
#define SEQ 2048
#define NHEADS 16
#define HSZ 64
#define NROWS 8192            // B*S = 4*2048
constexpr float SCALE = 0.125f;  // 1/sqrt(64)

typedef __attribute__((ext_vector_type(8))) short bf16x8;  // 8 bf16 (4 VGPRs)
typedef __attribute__((ext_vector_type(4))) float f32x4;   // 4 fp32 acc

__device__ __forceinline__ unsigned short f2bf(float f) {
  unsigned int u = __builtin_bit_cast(unsigned int, f);
  u = (u + 0x7fffu + ((u >> 16) & 1u)) >> 16;  // RNE
  return (unsigned short)u;
}

// ---------------------------------------------------------------------------
// Tiled fp32 GEMM: Y[n,o] = sum_h X[n,h] * W[o,h] + bias[o]
// Tile 128x128, BK=16, 256 threads, 8x8 micro-tile, k-major LDS tiles.
// MODE 0: fp32 row-major out.  MODE 1: bf16 out scattered to [B,NH,S,HS],
//         with (acc+bias)*scale applied (scale=0.125 for Q).
// ---------------------------------------------------------------------------
template <int MODE>
__device__ __forceinline__ void gemm_body(const float* __restrict__ X,
                                          const float* __restrict__ W,
                                          const float* __restrict__ bias,
                                          void* __restrict__ Yv, float scale) {
  __shared__ float As[16][132];  // [k][row], pad +4
  __shared__ float Bs[16][132];  // [k][col]

  const int t = threadIdx.x;
  const int tx = t & 15;   // cols
  const int ty = t >> 4;   // rows
  const int row0 = blockIdx.y * 128;
  const int col0 = blockIdx.x * 128;

  float acc[8][8];
#pragma unroll
  for (int i = 0; i < 8; ++i)
#pragma unroll
    for (int j = 0; j < 8; ++j) acc[i][j] = 0.0f;

  const int sr = t >> 2;         // staging row 0..63
  const int sk = (t & 3) << 2;   // staging k 0,4,8,12

  for (int k0 = 0; k0 < H; k0 += 16) {
#pragma unroll
    for (int p = 0; p < 2; ++p) {
      const int r = sr + 64 * p;
      float4 xa = *(const float4*)&X[(size_t)(row0 + r) * H + k0 + sk];
      As[sk + 0][r] = xa.x;
      As[sk + 1][r] = xa.y;
      As[sk + 2][r] = xa.z;
      As[sk + 3][r] = xa.w;
      float4 wb = *(const float4*)&W[(size_t)(col0 + r) * H + k0 + sk];
      Bs[sk + 0][r] = wb.x;
      Bs[sk + 1][r] = wb.y;
      Bs[sk + 2][r] = wb.z;
      Bs[sk + 3][r] = wb.w;
    }
    __syncthreads();
#pragma unroll
    for (int k = 0; k < 16; ++k) {
      float4 a0 = *(const float4*)&As[k][ty * 4];
      float4 a1 = *(const float4*)&As[k][ty * 4 + 64];
      float4 b0 = *(const float4*)&Bs[k][tx * 4];
      float4 b1 = *(const float4*)&Bs[k][tx * 4 + 64];
      float a[8] = {a0.x, a0.y, a0.z, a0.w, a1.x, a1.y, a1.z, a1.w};
      float b[8] = {b0.x, b0.y, b0.z, b0.w, b1.x, b1.y, b1.z, b1.w};
#pragma unroll
      for (int i = 0; i < 8; ++i)
#pragma unroll
        for (int j = 0; j < 8; ++j) acc[i][j] += a[i] * b[j];
    }
    __syncthreads();
  }

#pragma unroll
  for (int i = 0; i < 8; ++i) {
    const int r = row0 + ty * 4 + (i & 3) + (i >> 2) * 64;
#pragma unroll
    for (int jg = 0; jg < 2; ++jg) {
      const int c = col0 + tx * 4 + jg * 64;
      float4 bb = *(const float4*)&bias[c];
      float4 v;
      v.x = (acc[i][jg * 4 + 0] + bb.x) * scale;
      v.y = (acc[i][jg * 4 + 1] + bb.y) * scale;
      v.z = (acc[i][jg * 4 + 2] + bb.z) * scale;
      v.w = (acc[i][jg * 4 + 3] + bb.w) * scale;
      if (MODE == 1) {
        unsigned short* Y = (unsigned short*)Yv;
        const int b = r / SEQ, s = r % SEQ;
        const int head = c >> 6, hs = c & 63;
        ushort4 sv;
        sv.x = f2bf(v.x);
        sv.y = f2bf(v.y);
        sv.z = f2bf(v.z);
        sv.w = f2bf(v.w);
        *(ushort4*)&Y[(((size_t)(b * NHEADS + head) * SEQ + s) * HSZ) + hs] = sv;
      } else {
        float* Y = (float*)Yv;
        *(float4*)&Y[(size_t)r * H + c] = v;
      }
    }
  }
}

__global__ __launch_bounds__(256) void qkv_gemm(
    const float* __restrict__ X, const float* __restrict__ Wq,
    const float* __restrict__ bq, const float* __restrict__ Wk,
    const float* __restrict__ bk, const float* __restrict__ Wv,
    const float* __restrict__ bv, unsigned short* __restrict__ Qo,
    unsigned short* __restrict__ Ko, unsigned short* __restrict__ Vo) {
  const float* W;
  const float* bias;
  unsigned short* Y;
  float scale = 1.0f;
  if (blockIdx.z == 0) {
    W = Wq; bias = bq; Y = Qo; scale = SCALE;  // pre-scale Q
  } else if (blockIdx.z == 1) {
    W = Wk; bias = bk; Y = Ko;
  } else {
    W = Wv; bias = bv; Y = Vo;
  }
  gemm_body<1>(X, W, bias, Y, scale);
}

__global__ __launch_bounds__(256) void out_gemm(const float* __restrict__ X,
                                                const float* __restrict__ W,
                                                const float* __restrict__ bias,
                                                float* __restrict__ Y) {
  gemm_body<0>(X, W, bias, Y, 1.0f);
}

// ---------------------------------------------------------------------------
// V transpose: [B,NH,S,HS] bf16 -> [B,NH,HS,S] bf16, 64x64 tiles.
// ---------------------------------------------------------------------------
__global__ __launch_bounds__(256) void transpose_v(
    const unsigned short* __restrict__ V, unsigned short* __restrict__ VT) {
  __shared__ unsigned short T[64][65];
  const int t = threadIdx.x;
  const int st = blockIdx.x, h = blockIdx.y, b = blockIdx.z;
  const unsigned short* src =
      V + ((size_t)(b * NHEADS + h) * SEQ + (size_t)st * 64) * HSZ;
  unsigned short* dst = VT + (size_t)(b * NHEADS + h) * HSZ * SEQ;

  const int sr = t >> 3;        // 0..31
  const int sc = (t & 7) * 8;   // 0..56
#pragma unroll
  for (int p = 0; p < 2; ++p) {
    const int row = sr + 32 * p;  // s within tile
    union { uint4 u; unsigned short s[8]; } cv;
    cv.u = *(const uint4*)&src[(size_t)row * HSZ + sc];
#pragma unroll
    for (int e = 0; e < 8; ++e) T[row][sc + e] = cv.s[e];
  }
  __syncthreads();
#pragma unroll
  for (int p = 0; p < 2; ++p) {
    const int d = sr + 32 * p;
    union { uint4 u; unsigned short s[8]; } ov;
#pragma unroll
    for (int e = 0; e < 8; ++e) ov.s[e] = T[sc + e][d];
    *(uint4*)&dst[(size_t)d * SEQ + (size_t)st * 64 + sc] = ov.u;
  }
}

// ---------------------------------------------------------------------------
// MFMA flash attention. Block = 256 thr = 4 waves; wave w owns 16 q-rows.
// Q pre-scaled bf16 [B,NH,S,64]; K bf16 [B,NH,S,64]; VT bf16 [B,NH,64,S].
// Per 64-key tile: 8 QK mfma + softmax (fp32, 16-lane shfl reduce) + 8 PV mfma.
// Frag layouts (m89-verified): C/D: col = l&15, row = 4*(l>>4)+reg.
// A/B loaded with the SAME position->k content map (k = 32c+8g+e), so the
// k-permutation cancels between operands.
// Ps is PER-WAVE ([4][16][72]) — round-2 bug was all 4 waves racing on one
// shared 16-row P buffer.
// ---------------------------------------------------------------------------
__global__ __launch_bounds__(256) void attn_mfma(
    const unsigned short* __restrict__ Q, const unsigned short* __restrict__ K,
    const unsigned short* __restrict__ VT, float* __restrict__ CTX) {
  __shared__ unsigned short Ks[64][72];     // [k][d]
  __shared__ unsigned short Vs[64][72];     // [d][k]  (VT tile)
  __shared__ unsigned short Ps[4][16][72];  // per-wave [q][k] bf16 P

  const int t = threadIdx.x;
  const int lane = t & 63;
  const int w = t >> 6;        // wave 0..3
  const int lr = lane & 15;
  const int g = lane >> 4;     // 0..3
  const int qt = blockIdx.x, h = blockIdx.y, b = blockIdx.z;

  const size_t base = (size_t)(b * NHEADS + h) * SEQ * HSZ;
  const unsigned short* Qg = Q + base + (size_t)(qt * 64 + w * 16) * HSZ;
  const unsigned short* Kg = K + base;
  const unsigned short* Vg = VT + base;  // [64][SEQ]

  // Q fragments in registers: lane holds Q[w*16+lr][8g+32c+e]
  bf16x8 qf[2];
  qf[0] = *(const bf16x8*)&Qg[(size_t)lr * HSZ + 8 * g];
  qf[1] = *(const bf16x8*)&Qg[(size_t)lr * HSZ + 8 * g + 32];

  float m_[4], l_[4];
  f32x4 oacc[4];
#pragma unroll
  for (int r = 0; r < 4; ++r) {
    m_[r] = -INFINITY;
    l_[r] = 0.0f;
  }
#pragma unroll
  for (int dt = 0; dt < 4; ++dt) oacc[dt] = (f32x4){0.f, 0.f, 0.f, 0.f};

  const int sr = t >> 3;        // 0..31 staging row
  const int sc = (t & 7) * 8;   // 0..56 staging col

  for (int kt = 0; kt < SEQ / 64; ++kt) {
    __syncthreads();  // prev-iter PV readers done
#pragma unroll
    for (int p = 0; p < 2; ++p) {
      const int row = sr + 32 * p;
      *(uint4*)&Ks[row][sc] =
          *(const uint4*)&Kg[(size_t)(kt * 64 + row) * HSZ + sc];
      *(uint4*)&Vs[row][sc] =
          *(const uint4*)&Vg[(size_t)row * SEQ + (size_t)kt * 64 + sc];
    }
    __syncthreads();

    // QK^T: sacc[j] = S[16q x 16k], keys lr+16j
    f32x4 sacc[4];
#pragma unroll
    for (int j = 0; j < 4; ++j) sacc[j] = (f32x4){0.f, 0.f, 0.f, 0.f};
#pragma unroll
    for (int c = 0; c < 2; ++c) {
#pragma unroll
      for (int j = 0; j < 4; ++j) {
        bf16x8 kf = *(const bf16x8*)&Ks[16 * j + lr][8 * g + 32 * c];
        sacc[j] =
            __builtin_amdgcn_mfma_f32_16x16x32_bf16(qf[c], kf, sacc[j], 0, 0, 0);
      }
    }

    // online softmax per q-row (wave-relative row = 4g+r), 16-lane reduce
#pragma unroll
    for (int r = 0; r < 4; ++r) {
      float rm = fmaxf(fmaxf(sacc[0][r], sacc[1][r]),
                       fmaxf(sacc[2][r], sacc[3][r]));
      rm = fmaxf(rm, __shfl_xor(rm, 1));
      rm = fmaxf(rm, __shfl_xor(rm, 2));
      rm = fmaxf(rm, __shfl_xor(rm, 4));
      rm = fmaxf(rm, __shfl_xor(rm, 8));
      const float mn = fmaxf(m_[r], rm);
      const float al = __expf(m_[r] - mn);
      m_[r] = mn;
      float p0 = __expf(sacc[0][r] - mn);
      float p1 = __expf(sacc[1][r] - mn);
      float p2 = __expf(sacc[2][r] - mn);
      float p3 = __expf(sacc[3][r] - mn);
      float rs = p0 + p1 + p2 + p3;
      rs += __shfl_xor(rs, 1);
      rs += __shfl_xor(rs, 2);
      rs += __shfl_xor(rs, 4);
      rs += __shfl_xor(rs, 8);
      l_[r] = l_[r] * al + rs;
#pragma unroll
      for (int dt = 0; dt < 4; ++dt) oacc[dt][r] *= al;
      const int qrow = 4 * g + r;  // wave-relative
      Ps[w][qrow][lr + 0] = f2bf(p0);
      Ps[w][qrow][lr + 16] = f2bf(p1);
      Ps[w][qrow][lr + 32] = f2bf(p2);
      Ps[w][qrow][lr + 48] = f2bf(p3);
    }
    __syncthreads();

    // PV: oacc[dt] += P[16q x 64k] * V[64k x 16d]
#pragma unroll
    for (int c = 0; c < 2; ++c) {
      bf16x8 pf = *(const bf16x8*)&Ps[w][lr][8 * g + 32 * c];
#pragma unroll
      for (int dt = 0; dt < 4; ++dt) {
        bf16x8 vf = *(const bf16x8*)&Vs[lr + 16 * dt][8 * g + 32 * c];
        oacc[dt] =
            __builtin_amdgcn_mfma_f32_16x16x32_bf16(pf, vf, oacc[dt], 0, 0, 0);
      }
    }
  }

  // epilogue: normalize, write ctx [B,S,H] fp32
#pragma unroll
  for (int r = 0; r < 4; ++r) {
    const float inv = 1.0f / l_[r];
    const int qrow = qt * 64 + w * 16 + 4 * g + r;
#pragma unroll
    for (int dt = 0; dt < 4; ++dt) {
      CTX[((size_t)b * SEQ + qrow) * H + h * HSZ + lr + 16 * dt] =
          oacc[dt][r] * inv;
    }
  }
}

// ---------------------------------------------------------------------------
extern "C" void kernel_launch(void* const* d_in, const int* in_sizes, int n_in,
                              void* d_out, int out_size, void* d_ws,
                              size_t ws_size, hipStream_t stream) {
  const float* x = (const float*)d_in[0];
  const float* Wq = (const float*)d_in[1];
  const float* bq = (const float*)d_in[2];
  const float* Wk = (const float*)d_in[3];
  const float* bk = (const float*)d_in[4];
  const float* Wv = (const float*)d_in[5];
  const float* bv = (const float*)d_in[6];
  const float* Wo = (const float*)d_in[7];
  const float* bo = (const float*)d_in[8];

  const size_t PER = (size_t)4 * NHEADS * SEQ * HSZ;  // 8388608 elems
  unsigned short* Qb = (unsigned short*)d_ws;
  unsigned short* Kb = Qb + PER;
  unsigned short* Vb = Kb + PER;
  unsigned short* VTb = Vb + PER;
  float* CTX = (float*)(VTb + PER);

  qkv_gemm<<<dim3(H / 128, NROWS / 128, 3), 256, 0, stream>>>(
      x, Wq, bq, Wk, bk, Wv, bv, Qb, Kb, Vb);

  transpose_v<<<dim3(SEQ / 64, NHEADS, 4), 256, 0, stream>>>(Vb, VTb);

  attn_mfma<<<dim3(SEQ / 64, NHEADS, 4), 256, 0, stream>>>(Qb, Kb, VTb, CTX);

  out_gemm<<<dim3(H / 128, NROWS / 128), 256, 0, stream>>>(CTX, Wo, bo,
                                                           (float*)d_out);
}

// Round 4
// 372.180 us; speedup vs baseline: 6.1473x; 2.7132x over previous
//
#include <hip/hip_runtime.h>
#include <math.h>

#define H 1024
#define SEQ 2048
#define NHEADS 16
#define HSZ 64
#define NROWS 8192            // B*S = 4*2048
constexpr float SCALE = 0.125f;  // 1/sqrt(64)

typedef unsigned short u16;
typedef __attribute__((ext_vector_type(8))) short bf16x8;  // 8 bf16 (4 VGPRs)
typedef __attribute__((ext_vector_type(4))) float f32x4;   // 4 fp32 acc

__device__ __forceinline__ u16 f2bf(float f) {
  unsigned int u = __builtin_bit_cast(unsigned int, f);
  u = (u + 0x7fffu + ((u >> 16) & 1u)) >> 16;  // RNE
  return (u16)u;
}
__device__ __forceinline__ float bf2f(u16 h) {
  return __builtin_bit_cast(float, (unsigned int)h << 16);
}

// async global->LDS, 16B per lane. LDS dest = wave-uniform base + lane*16.
__device__ __forceinline__ void gload_lds16(const void* g, void* l) {
  unsigned long long ga = (unsigned long long)g;
  unsigned int la = (unsigned int)(unsigned long long)l;  // low32 = LDS offset
  __builtin_amdgcn_global_load_lds(
      (const __attribute__((address_space(1))) unsigned int*)ga,
      (__attribute__((address_space(3))) unsigned int*)la, 16, 0, 0);
}

// ---------------------------------------------------------------------------
// Cast kernels (one-time, memory-bound)
// ---------------------------------------------------------------------------
__global__ __launch_bounds__(256) void cast_x(const float* __restrict__ x,
                                              u16* __restrict__ Xb) {
  const int n4 = NROWS * H / 4;
  for (int i = blockIdx.x * blockDim.x + threadIdx.x; i < n4;
       i += gridDim.x * blockDim.x) {
    float4 v = ((const float4*)x)[i];
    ushort4 o;
    o.x = f2bf(v.x); o.y = f2bf(v.y); o.z = f2bf(v.z); o.w = f2bf(v.w);
    ((ushort4*)Xb)[i] = o;
  }
}

__global__ __launch_bounds__(256) void cast_w(
    const float* __restrict__ Wq, const float* __restrict__ Wk,
    const float* __restrict__ Wv, const float* __restrict__ Wo,
    u16* __restrict__ Wqb, u16* __restrict__ Wkb, u16* __restrict__ Wvb,
    u16* __restrict__ Wohi, u16* __restrict__ Wolo) {
  const int n4 = H * H / 4;
  const int which = blockIdx.y;
  const float* src = which == 0 ? Wq : which == 1 ? Wk : which == 2 ? Wv : Wo;
  for (int i = blockIdx.x * blockDim.x + threadIdx.x; i < n4;
       i += gridDim.x * blockDim.x) {
    float4 v = ((const float4*)src)[i];
    if (which < 3) {
      u16* dst = which == 0 ? Wqb : which == 1 ? Wkb : Wvb;
      ushort4 o;
      o.x = f2bf(v.x); o.y = f2bf(v.y); o.z = f2bf(v.z); o.w = f2bf(v.w);
      ((ushort4*)dst)[i] = o;
    } else {
      ushort4 hi, lo;
      hi.x = f2bf(v.x); lo.x = f2bf(v.x - bf2f(hi.x));
      hi.y = f2bf(v.y); lo.y = f2bf(v.y - bf2f(hi.y));
      hi.z = f2bf(v.z); lo.z = f2bf(v.z - bf2f(hi.z));
      hi.w = f2bf(v.w); lo.w = f2bf(v.w - bf2f(hi.w));
      ((ushort4*)Wohi)[i] = hi;
      ((ushort4*)Wolo)[i] = lo;
    }
  }
}

// ---------------------------------------------------------------------------
// MFMA GEMM building blocks. Tile 128x128, BK=64, 4 waves (2x2), each wave
// owns 64x64 = 4x4 fragments of 16x16x32 bf16 MFMA.
// LDS tiles [128 rows][64 k] bf16, LINEAR (global_load_lds dest), with the
// 16B k-slot XOR-swizzled on the GLOBAL source and on the ds_read (rule #21):
// LDS (r, slot) holds global slot^(r&7); reader wants slot s -> reads s^(r&7).
// Spreads the 128B-row-stride fragment reads across 8 bank groups.
// ---------------------------------------------------------------------------
__device__ __forceinline__ void stage_tile(const u16* __restrict__ gbase,
                                           int row0, int k0,
                                           u16* __restrict__ lds, int t) {
  const int rl = t >> 3;   // 0..31
  const int sl = t & 7;    // 16B slot
#pragma unroll
  for (int c = 0; c < 4; ++c) {
    const int r = c * 32 + rl;
    const int slot = sl ^ (r & 7);
    gload_lds16(gbase + (size_t)(row0 + r) * H + k0 + slot * 8,
                lds + (size_t)t * 8 + c * 2048);
  }
}

__device__ __forceinline__ void wave_frags(const u16* __restrict__ Ts, int w64,
                                           int lr, int g, int kk,
                                           bf16x8 f[4]) {
#pragma unroll
  for (int m = 0; m < 4; ++m) {
    const int row = w64 + m * 16 + lr;
    const int slot = (4 * kk + g) ^ (row & 7);
    f[m] = *(const bf16x8*)&Ts[row * 64 + slot * 8];
  }
}

__device__ __forceinline__ void wave_mma_step(const u16* As, const u16* Bs,
                                              int wr, int wc, int lr, int g,
                                              f32x4 acc[4][4]) {
#pragma unroll
  for (int kk = 0; kk < 2; ++kk) {
    bf16x8 af[4], bfr[4];
    wave_frags(As, wr * 64, lr, g, kk, af);
    wave_frags(Bs, wc * 64, lr, g, kk, bfr);
#pragma unroll
    for (int m = 0; m < 4; ++m)
#pragma unroll
      for (int n = 0; n < 4; ++n)
        acc[m][n] = __builtin_amdgcn_mfma_f32_16x16x32_bf16(af[m], bfr[n],
                                                            acc[m][n], 0, 0, 0);
  }
}

// QKV projection: Y = bf16((X*W^T + b)*scale) scattered to [B,NH,S,HS].
__global__ __launch_bounds__(256) void qkv_mfma(
    const u16* __restrict__ Xb, const u16* __restrict__ Wqb,
    const u16* __restrict__ Wkb, const u16* __restrict__ Wvb,
    const float* __restrict__ bq, const float* __restrict__ bk,
    const float* __restrict__ bv, u16* __restrict__ Qo, u16* __restrict__ Ko,
    u16* __restrict__ Vo) {
  __shared__ u16 As[128 * 64];
  __shared__ u16 Bs[128 * 64];

  const u16* Wb;
  const float* bias;
  u16* Y;
  float scale = 1.0f;
  if (blockIdx.z == 0) {
    Wb = Wqb; bias = bq; Y = Qo; scale = SCALE;
  } else if (blockIdx.z == 1) {
    Wb = Wkb; bias = bk; Y = Ko;
  } else {
    Wb = Wvb; bias = bv; Y = Vo;
  }

  const int t = threadIdx.x;
  const int lane = t & 63, w = t >> 6;
  const int lr = lane & 15, g = lane >> 4;
  const int wr = w >> 1, wc = w & 1;
  const int row0 = blockIdx.y * 128, col0 = blockIdx.x * 128;

  f32x4 acc[4][4];
#pragma unroll
  for (int m = 0; m < 4; ++m)
#pragma unroll
    for (int n = 0; n < 4; ++n) acc[m][n] = (f32x4){0.f, 0.f, 0.f, 0.f};

  for (int k0 = 0; k0 < H; k0 += 64) {
    __syncthreads();
    stage_tile(Xb, row0, k0, As, t);
    stage_tile(Wb, col0, k0, Bs, t);
    __syncthreads();  // compiler drains vmcnt before s_barrier
    wave_mma_step(As, Bs, wr, wc, lr, g, acc);
  }

#pragma unroll
  for (int m = 0; m < 4; ++m) {
    const int row = row0 + wr * 64 + m * 16 + 4 * g;
#pragma unroll
    for (int n = 0; n < 4; ++n) {
      const int col = col0 + wc * 64 + n * 16 + lr;
      const int head = col >> 6, hs = col & 63;
      const float bb = bias[col];
#pragma unroll
      for (int r = 0; r < 4; ++r) {
        const int rr = row + r;
        const int b = rr >> 11, s = rr & 2047;
        Y[((size_t)(b * NHEADS + head) * SEQ + s) * HSZ + hs] =
            f2bf((acc[m][n][r] + bb) * scale);
      }
    }
  }
}

// Out projection, split precision: out = (Ah+Al)*(Bh+Bl)^T ~ AhBh+AhBl+AlBh.
__global__ __launch_bounds__(256) void out_mfma(
    const u16* __restrict__ Ahi, const u16* __restrict__ Alo,
    const u16* __restrict__ Bhi, const u16* __restrict__ Blo,
    const float* __restrict__ bias, float* __restrict__ Y) {
  __shared__ u16 AsH[128 * 64];
  __shared__ u16 AsL[128 * 64];
  __shared__ u16 BsH[128 * 64];
  __shared__ u16 BsL[128 * 64];

  const int t = threadIdx.x;
  const int lane = t & 63, w = t >> 6;
  const int lr = lane & 15, g = lane >> 4;
  const int wr = w >> 1, wc = w & 1;
  const int row0 = blockIdx.y * 128, col0 = blockIdx.x * 128;

  f32x4 acc[4][4];
#pragma unroll
  for (int m = 0; m < 4; ++m)
#pragma unroll
    for (int n = 0; n < 4; ++n) acc[m][n] = (f32x4){0.f, 0.f, 0.f, 0.f};

  for (int k0 = 0; k0 < H; k0 += 64) {
    __syncthreads();
    stage_tile(Ahi, row0, k0, AsH, t);
    stage_tile(Alo, row0, k0, AsL, t);
    stage_tile(Bhi, col0, k0, BsH, t);
    stage_tile(Blo, col0, k0, BsL, t);
    __syncthreads();
#pragma unroll
    for (int kk = 0; kk < 2; ++kk) {
      bf16x8 ah[4], al[4], bh[4], bl[4];
      wave_frags(AsH, wr * 64, lr, g, kk, ah);
      wave_frags(AsL, wr * 64, lr, g, kk, al);
      wave_frags(BsH, wc * 64, lr, g, kk, bh);
      wave_frags(BsL, wc * 64, lr, g, kk, bl);
#pragma unroll
      for (int m = 0; m < 4; ++m)
#pragma unroll
        for (int n = 0; n < 4; ++n) {
          acc[m][n] = __builtin_amdgcn_mfma_f32_16x16x32_bf16(ah[m], bh[n],
                                                              acc[m][n], 0, 0, 0);
          acc[m][n] = __builtin_amdgcn_mfma_f32_16x16x32_bf16(ah[m], bl[n],
                                                              acc[m][n], 0, 0, 0);
          acc[m][n] = __builtin_amdgcn_mfma_f32_16x16x32_bf16(al[m], bh[n],
                                                              acc[m][n], 0, 0, 0);
        }
    }
  }

#pragma unroll
  for (int m = 0; m < 4; ++m) {
    const int row = row0 + wr * 64 + m * 16 + 4 * g;
#pragma unroll
    for (int n = 0; n < 4; ++n) {
      const int col = col0 + wc * 64 + n * 16 + lr;
      const float bb = bias[col];
#pragma unroll
      for (int r = 0; r < 4; ++r)
        Y[(size_t)(row + r) * H + col] = acc[m][n][r] + bb;
    }
  }
}

// ---------------------------------------------------------------------------
// V transpose: [B,NH,S,HS] bf16 -> [B,NH,HS,S] bf16, 64x64 tiles.
// ---------------------------------------------------------------------------
__global__ __launch_bounds__(256) void transpose_v(const u16* __restrict__ V,
                                                   u16* __restrict__ VT) {
  __shared__ u16 T[64][65];
  const int t = threadIdx.x;
  const int st = blockIdx.x, h = blockIdx.y, b = blockIdx.z;
  const u16* src = V + ((size_t)(b * NHEADS + h) * SEQ + (size_t)st * 64) * HSZ;
  u16* dst = VT + (size_t)(b * NHEADS + h) * HSZ * SEQ;

  const int sr = t >> 3;
  const int sc = (t & 7) * 8;
#pragma unroll
  for (int p = 0; p < 2; ++p) {
    const int row = sr + 32 * p;
    union { uint4 u; u16 s[8]; } cv;
    cv.u = *(const uint4*)&src[(size_t)row * HSZ + sc];
#pragma unroll
    for (int e = 0; e < 8; ++e) T[row][sc + e] = cv.s[e];
  }
  __syncthreads();
#pragma unroll
  for (int p = 0; p < 2; ++p) {
    const int d = sr + 32 * p;
    union { uint4 u; u16 s[8]; } ov;
#pragma unroll
    for (int e = 0; e < 8; ++e) ov.s[e] = T[sc + e][d];
    *(uint4*)&dst[(size_t)d * SEQ + (size_t)st * 64 + sc] = ov.u;
  }
}

// ---------------------------------------------------------------------------
// MFMA flash attention (round-3 verified). Epilogue now emits ctx as hi/lo
// bf16 planes for the split-precision out projection.
// ---------------------------------------------------------------------------
__global__ __launch_bounds__(256) void attn_mfma(
    const u16* __restrict__ Q, const u16* __restrict__ K,
    const u16* __restrict__ VT, u16* __restrict__ CTXhi,
    u16* __restrict__ CTXlo) {
  __shared__ u16 Ks[64][72];
  __shared__ u16 Vs[64][72];
  __shared__ u16 Ps[4][16][72];  // per-wave P

  const int t = threadIdx.x;
  const int lane = t & 63;
  const int w = t >> 6;
  const int lr = lane & 15;
  const int g = lane >> 4;
  const int qt = blockIdx.x, h = blockIdx.y, b = blockIdx.z;

  const size_t base = (size_t)(b * NHEADS + h) * SEQ * HSZ;
  const u16* Qg = Q + base + (size_t)(qt * 64 + w * 16) * HSZ;
  const u16* Kg = K + base;
  const u16* Vg = VT + base;  // [64][SEQ]

  bf16x8 qf[2];
  qf[0] = *(const bf16x8*)&Qg[(size_t)lr * HSZ + 8 * g];
  qf[1] = *(const bf16x8*)&Qg[(size_t)lr * HSZ + 8 * g + 32];

  float m_[4], l_[4];
  f32x4 oacc[4];
#pragma unroll
  for (int r = 0; r < 4; ++r) {
    m_[r] = -INFINITY;
    l_[r] = 0.0f;
  }
#pragma unroll
  for (int dt = 0; dt < 4; ++dt) oacc[dt] = (f32x4){0.f, 0.f, 0.f, 0.f};

  const int sr = t >> 3;
  const int sc = (t & 7) * 8;

  for (int kt = 0; kt < SEQ / 64; ++kt) {
    __syncthreads();
#pragma unroll
    for (int p = 0; p < 2; ++p) {
      const int row = sr + 32 * p;
      *(uint4*)&Ks[row][sc] =
          *(const uint4*)&Kg[(size_t)(kt * 64 + row) * HSZ + sc];
      *(uint4*)&Vs[row][sc] =
          *(const uint4*)&Vg[(size_t)row * SEQ + (size_t)kt * 64 + sc];
    }
    __syncthreads();

    f32x4 sacc[4];
#pragma unroll
    for (int j = 0; j < 4; ++j) sacc[j] = (f32x4){0.f, 0.f, 0.f, 0.f};
#pragma unroll
    for (int c = 0; c < 2; ++c) {
#pragma unroll
      for (int j = 0; j < 4; ++j) {
        bf16x8 kf = *(const bf16x8*)&Ks[16 * j + lr][8 * g + 32 * c];
        sacc[j] =
            __builtin_amdgcn_mfma_f32_16x16x32_bf16(qf[c], kf, sacc[j], 0, 0, 0);
      }
    }

#pragma unroll
    for (int r = 0; r < 4; ++r) {
      float rm = fmaxf(fmaxf(sacc[0][r], sacc[1][r]),
                       fmaxf(sacc[2][r], sacc[3][r]));
      rm = fmaxf(rm, __shfl_xor(rm, 1));
      rm = fmaxf(rm, __shfl_xor(rm, 2));
      rm = fmaxf(rm, __shfl_xor(rm, 4));
      rm = fmaxf(rm, __shfl_xor(rm, 8));
      const float mn = fmaxf(m_[r], rm);
      const float al = __expf(m_[r] - mn);
      m_[r] = mn;
      float p0 = __expf(sacc[0][r] - mn);
      float p1 = __expf(sacc[1][r] - mn);
      float p2 = __expf(sacc[2][r] - mn);
      float p3 = __expf(sacc[3][r] - mn);
      float rs = p0 + p1 + p2 + p3;
      rs += __shfl_xor(rs, 1);
      rs += __shfl_xor(rs, 2);
      rs += __shfl_xor(rs, 4);
      rs += __shfl_xor(rs, 8);
      l_[r] = l_[r] * al + rs;
#pragma unroll
      for (int dt = 0; dt < 4; ++dt) oacc[dt][r] *= al;
      const int qrow = 4 * g + r;
      Ps[w][qrow][lr + 0] = f2bf(p0);
      Ps[w][qrow][lr + 16] = f2bf(p1);
      Ps[w][qrow][lr + 32] = f2bf(p2);
      Ps[w][qrow][lr + 48] = f2bf(p3);
    }
    __syncthreads();

#pragma unroll
    for (int c = 0; c < 2; ++c) {
      bf16x8 pf = *(const bf16x8*)&Ps[w][lr][8 * g + 32 * c];
#pragma unroll
      for (int dt = 0; dt < 4; ++dt) {
        bf16x8 vf = *(const bf16x8*)&Vs[lr + 16 * dt][8 * g + 32 * c];
        oacc[dt] =
            __builtin_amdgcn_mfma_f32_16x16x32_bf16(pf, vf, oacc[dt], 0, 0, 0);
      }
    }
  }

#pragma unroll
  for (int r = 0; r < 4; ++r) {
    const float inv = 1.0f / l_[r];
    const int qrow = qt * 64 + w * 16 + 4 * g + r;
#pragma unroll
    for (int dt = 0; dt < 4; ++dt) {
      const float val = oacc[dt][r] * inv;
      const u16 hi = f2bf(val);
      const u16 lo = f2bf(val - bf2f(hi));
      const size_t idx = ((size_t)b * SEQ + qrow) * H + h * HSZ + lr + 16 * dt;
      CTXhi[idx] = hi;
      CTXlo[idx] = lo;
    }
  }
}

// ---------------------------------------------------------------------------
extern "C" void kernel_launch(void* const* d_in, const int* in_sizes, int n_in,
                              void* d_out, int out_size, void* d_ws,
                              size_t ws_size, hipStream_t stream) {
  const float* x = (const float*)d_in[0];
  const float* Wq = (const float*)d_in[1];
  const float* bq = (const float*)d_in[2];
  const float* Wk = (const float*)d_in[3];
  const float* bk = (const float*)d_in[4];
  const float* Wv = (const float*)d_in[5];
  const float* bv = (const float*)d_in[6];
  const float* Wo = (const float*)d_in[7];
  const float* bo = (const float*)d_in[8];

  const size_t PER = (size_t)4 * NHEADS * SEQ * HSZ;  // 8388608
  const size_t WSZ = (size_t)H * H;                   // 1048576
  u16* Qb = (u16*)d_ws;
  u16* Kb = Qb + PER;
  u16* Vb = Kb + PER;
  u16* VTb = Vb + PER;
  u16* CTXhi = VTb + PER;
  u16* CTXlo = CTXhi + PER;
  u16* Xb = CTXlo + PER;
  u16* Wqb = Xb + PER;
  u16* Wkb = Wqb + WSZ;
  u16* Wvb = Wkb + WSZ;
  u16* Wohi = Wvb + WSZ;
  u16* Wolo = Wohi + WSZ;

  cast_x<<<2048, 256, 0, stream>>>(x, Xb);
  cast_w<<<dim3(256, 4), 256, 0, stream>>>(Wq, Wk, Wv, Wo, Wqb, Wkb, Wvb,
                                           Wohi, Wolo);

  qkv_mfma<<<dim3(H / 128, NROWS / 128, 3), 256, 0, stream>>>(
      Xb, Wqb, Wkb, Wvb, bq, bk, bv, Qb, Kb, Vb);

  transpose_v<<<dim3(SEQ / 64, NHEADS, 4), 256, 0, stream>>>(Vb, VTb);

  attn_mfma<<<dim3(SEQ / 64, NHEADS, 4), 256, 0, stream>>>(Qb, Kb, VTb, CTXhi,
                                                           CTXlo);

  out_mfma<<<dim3(H / 128, NROWS / 128), 256, 0, stream>>>(
      CTXhi, CTXlo, Wohi, Wolo, bo, (float*)d_out);
}

// Round 5
// 253.551 us; speedup vs baseline: 9.0234x; 1.4679x over previous
//
#include <hip/hip_runtime.h>
#include <math.h>

#define H 1024
#define SEQ 2048
#define NHEADS 16
#define HSZ 64
#define NROWS 8192            // B*S = 4*2048
constexpr float SCALE = 0.125f;  // 1/sqrt(64)

typedef unsigned short u16;
typedef __attribute__((ext_vector_type(8))) short bf16x8;   // 8 bf16 (4 VGPRs)
typedef __attribute__((ext_vector_type(4))) float f32x4;    // 4 fp32
typedef __attribute__((ext_vector_type(16))) float f32x16;  // 32x32 acc
typedef __attribute__((ext_vector_type(4))) unsigned int u32x4;

__device__ __forceinline__ u16 f2bf(float f) {
  unsigned int u = __builtin_bit_cast(unsigned int, f);
  u = (u + 0x7fffu + ((u >> 16) & 1u)) >> 16;  // RNE
  return (u16)u;
}
__device__ __forceinline__ float bf2f(u16 h) {
  return __builtin_bit_cast(float, (unsigned int)h << 16);
}

// async global->LDS, 16B per lane. LDS dest = wave-uniform base + lane*16.
__device__ __forceinline__ void gload_lds16(const void* g, void* l) {
  unsigned long long ga = (unsigned long long)g;
  unsigned int la = (unsigned int)(unsigned long long)l;
  __builtin_amdgcn_global_load_lds(
      (const __attribute__((address_space(1))) unsigned int*)ga,
      (__attribute__((address_space(3))) unsigned int*)la, 16, 0, 0);
}

// ---------------------------------------------------------------------------
// Cast kernels (one-time, memory-bound)
// ---------------------------------------------------------------------------
__global__ __launch_bounds__(256) void cast_x(const float* __restrict__ x,
                                              u16* __restrict__ Xb) {
  const int n4 = NROWS * H / 4;
  for (int i = blockIdx.x * blockDim.x + threadIdx.x; i < n4;
       i += gridDim.x * blockDim.x) {
    float4 v = ((const float4*)x)[i];
    ushort4 o;
    o.x = f2bf(v.x); o.y = f2bf(v.y); o.z = f2bf(v.z); o.w = f2bf(v.w);
    ((ushort4*)Xb)[i] = o;
  }
}

__global__ __launch_bounds__(256) void cast_w(
    const float* __restrict__ Wq, const float* __restrict__ Wk,
    const float* __restrict__ Wv, const float* __restrict__ Wo,
    u16* __restrict__ Wqb, u16* __restrict__ Wkb, u16* __restrict__ Wvb,
    u16* __restrict__ Wohi, u16* __restrict__ Wolo) {
  const int n4 = H * H / 4;
  const int which = blockIdx.y;
  const float* src = which == 0 ? Wq : which == 1 ? Wk : which == 2 ? Wv : Wo;
  for (int i = blockIdx.x * blockDim.x + threadIdx.x; i < n4;
       i += gridDim.x * blockDim.x) {
    float4 v = ((const float4*)src)[i];
    if (which < 3) {
      u16* dst = which == 0 ? Wqb : which == 1 ? Wkb : Wvb;
      ushort4 o;
      o.x = f2bf(v.x); o.y = f2bf(v.y); o.z = f2bf(v.z); o.w = f2bf(v.w);
      ((ushort4*)dst)[i] = o;
    } else {
      ushort4 hi, lo;
      hi.x = f2bf(v.x); lo.x = f2bf(v.x - bf2f(hi.x));
      hi.y = f2bf(v.y); lo.y = f2bf(v.y - bf2f(hi.y));
      hi.z = f2bf(v.z); lo.z = f2bf(v.z - bf2f(hi.z));
      hi.w = f2bf(v.w); lo.w = f2bf(v.w - bf2f(hi.w));
      ((ushort4*)Wohi)[i] = hi;
      ((ushort4*)Wolo)[i] = lo;
    }
  }
}

// ---------------------------------------------------------------------------
// MFMA GEMM (verified R4). Tile 128x128, BK=64, 4 waves, 16x16x32 frags.
// ---------------------------------------------------------------------------
__device__ __forceinline__ void stage_tile(const u16* __restrict__ gbase,
                                           int row0, int k0,
                                           u16* __restrict__ lds, int t) {
  const int rl = t >> 3;
  const int sl = t & 7;
#pragma unroll
  for (int c = 0; c < 4; ++c) {
    const int r = c * 32 + rl;
    const int slot = sl ^ (r & 7);
    gload_lds16(gbase + (size_t)(row0 + r) * H + k0 + slot * 8,
                lds + (size_t)t * 8 + c * 2048);
  }
}

__device__ __forceinline__ void wave_frags(const u16* __restrict__ Ts, int w64,
                                           int lr, int g, int kk,
                                           bf16x8 f[4]) {
#pragma unroll
  for (int m = 0; m < 4; ++m) {
    const int row = w64 + m * 16 + lr;
    const int slot = (4 * kk + g) ^ (row & 7);
    f[m] = *(const bf16x8*)&Ts[row * 64 + slot * 8];
  }
}

__device__ __forceinline__ void wave_mma_step(const u16* As, const u16* Bs,
                                              int wr, int wc, int lr, int g,
                                              f32x4 acc[4][4]) {
#pragma unroll
  for (int kk = 0; kk < 2; ++kk) {
    bf16x8 af[4], bfr[4];
    wave_frags(As, wr * 64, lr, g, kk, af);
    wave_frags(Bs, wc * 64, lr, g, kk, bfr);
#pragma unroll
    for (int m = 0; m < 4; ++m)
#pragma unroll
      for (int n = 0; n < 4; ++n)
        acc[m][n] = __builtin_amdgcn_mfma_f32_16x16x32_bf16(af[m], bfr[n],
                                                            acc[m][n], 0, 0, 0);
  }
}

__global__ __launch_bounds__(256) void qkv_mfma(
    const u16* __restrict__ Xb, const u16* __restrict__ Wqb,
    const u16* __restrict__ Wkb, const u16* __restrict__ Wvb,
    const float* __restrict__ bq, const float* __restrict__ bk,
    const float* __restrict__ bv, u16* __restrict__ Qo, u16* __restrict__ Ko,
    u16* __restrict__ Vo) {
  __shared__ u16 As[128 * 64];
  __shared__ u16 Bs[128 * 64];

  const u16* Wb;
  const float* bias;
  u16* Y;
  float scale = 1.0f;
  if (blockIdx.z == 0) {
    Wb = Wqb; bias = bq; Y = Qo; scale = SCALE;
  } else if (blockIdx.z == 1) {
    Wb = Wkb; bias = bk; Y = Ko;
  } else {
    Wb = Wvb; bias = bv; Y = Vo;
  }

  const int t = threadIdx.x;
  const int lane = t & 63, w = t >> 6;
  const int lr = lane & 15, g = lane >> 4;
  const int wr = w >> 1, wc = w & 1;
  const int row0 = blockIdx.y * 128, col0 = blockIdx.x * 128;

  f32x4 acc[4][4];
#pragma unroll
  for (int m = 0; m < 4; ++m)
#pragma unroll
    for (int n = 0; n < 4; ++n) acc[m][n] = (f32x4){0.f, 0.f, 0.f, 0.f};

  for (int k0 = 0; k0 < H; k0 += 64) {
    __syncthreads();
    stage_tile(Xb, row0, k0, As, t);
    stage_tile(Wb, col0, k0, Bs, t);
    __syncthreads();
    wave_mma_step(As, Bs, wr, wc, lr, g, acc);
  }

#pragma unroll
  for (int m = 0; m < 4; ++m) {
    const int row = row0 + wr * 64 + m * 16 + 4 * g;
#pragma unroll
    for (int n = 0; n < 4; ++n) {
      const int col = col0 + wc * 64 + n * 16 + lr;
      const int head = col >> 6, hs = col & 63;
      const float bb = bias[col];
#pragma unroll
      for (int r = 0; r < 4; ++r) {
        const int rr = row + r;
        const int b = rr >> 11, s = rr & 2047;
        Y[((size_t)(b * NHEADS + head) * SEQ + s) * HSZ + hs] =
            f2bf((acc[m][n][r] + bb) * scale);
      }
    }
  }
}

__global__ __launch_bounds__(256) void out_mfma(
    const u16* __restrict__ Ahi, const u16* __restrict__ Alo,
    const u16* __restrict__ Bhi, const u16* __restrict__ Blo,
    const float* __restrict__ bias, float* __restrict__ Y) {
  __shared__ u16 AsH[128 * 64];
  __shared__ u16 AsL[128 * 64];
  __shared__ u16 BsH[128 * 64];
  __shared__ u16 BsL[128 * 64];

  const int t = threadIdx.x;
  const int lane = t & 63, w = t >> 6;
  const int lr = lane & 15, g = lane >> 4;
  const int wr = w >> 1, wc = w & 1;
  const int row0 = blockIdx.y * 128, col0 = blockIdx.x * 128;

  f32x4 acc[4][4];
#pragma unroll
  for (int m = 0; m < 4; ++m)
#pragma unroll
    for (int n = 0; n < 4; ++n) acc[m][n] = (f32x4){0.f, 0.f, 0.f, 0.f};

  for (int k0 = 0; k0 < H; k0 += 64) {
    __syncthreads();
    stage_tile(Ahi, row0, k0, AsH, t);
    stage_tile(Alo, row0, k0, AsL, t);
    stage_tile(Bhi, col0, k0, BsH, t);
    stage_tile(Blo, col0, k0, BsL, t);
    __syncthreads();
#pragma unroll
    for (int kk = 0; kk < 2; ++kk) {
      bf16x8 ah[4], al[4], bh[4], bl[4];
      wave_frags(AsH, wr * 64, lr, g, kk, ah);
      wave_frags(AsL, wr * 64, lr, g, kk, al);
      wave_frags(BsH, wc * 64, lr, g, kk, bh);
      wave_frags(BsL, wc * 64, lr, g, kk, bl);
#pragma unroll
      for (int m = 0; m < 4; ++m)
#pragma unroll
        for (int n = 0; n < 4; ++n) {
          acc[m][n] = __builtin_amdgcn_mfma_f32_16x16x32_bf16(ah[m], bh[n],
                                                              acc[m][n], 0, 0, 0);
          acc[m][n] = __builtin_amdgcn_mfma_f32_16x16x32_bf16(ah[m], bl[n],
                                                              acc[m][n], 0, 0, 0);
          acc[m][n] = __builtin_amdgcn_mfma_f32_16x16x32_bf16(al[m], bh[n],
                                                              acc[m][n], 0, 0, 0);
        }
    }
  }

#pragma unroll
  for (int m = 0; m < 4; ++m) {
    const int row = row0 + wr * 64 + m * 16 + 4 * g;
#pragma unroll
    for (int n = 0; n < 4; ++n) {
      const int col = col0 + wc * 64 + n * 16 + lr;
      const float bb = bias[col];
#pragma unroll
      for (int r = 0; r < 4; ++r)
        Y[(size_t)(row + r) * H + col] = acc[m][n][r] + bb;
    }
  }
}

// ---------------------------------------------------------------------------
// V transpose: [B,NH,S,HS] bf16 -> [B,NH,HS,S] bf16, 64x64 tiles.
// ---------------------------------------------------------------------------
__global__ __launch_bounds__(256) void transpose_v(const u16* __restrict__ V,
                                                   u16* __restrict__ VT) {
  __shared__ u16 T[64][65];
  const int t = threadIdx.x;
  const int st = blockIdx.x, h = blockIdx.y, b = blockIdx.z;
  const u16* src = V + ((size_t)(b * NHEADS + h) * SEQ + (size_t)st * 64) * HSZ;
  u16* dst = VT + (size_t)(b * NHEADS + h) * HSZ * SEQ;

  const int sr = t >> 3;
  const int sc = (t & 7) * 8;
#pragma unroll
  for (int p = 0; p < 2; ++p) {
    const int row = sr + 32 * p;
    union { uint4 u; u16 s[8]; } cv;
    cv.u = *(const uint4*)&src[(size_t)row * HSZ + sc];
#pragma unroll
    for (int e = 0; e < 8; ++e) T[row][sc + e] = cv.s[e];
  }
  __syncthreads();
#pragma unroll
  for (int p = 0; p < 2; ++p) {
    const int d = sr + 32 * p;
    union { uint4 u; u16 s[8]; } ov;
#pragma unroll
    for (int e = 0; e < 8; ++e) ov.s[e] = T[sc + e][d];
    *(uint4*)&dst[(size_t)d * SEQ + (size_t)st * 64 + sc] = ov.u;
  }
}

// ---------------------------------------------------------------------------
// Swapped-operand 32x32x16 MFMA flash attention.
// Block = 4 waves x 64 q-rows = 256 q. Wave processes 2 q-subtiles of 32.
// QK: D[key][q] = mfma(A=K, B=Q)  -> lane owns q = lane&31, 16 keys in regs.
// Softmax fully in-lane (tree + shfl_xor(32)); defer-max (THR=8).
// P -> PV B-frag via 8 cvt_pk_bf16 + 4 permlane32_swap (no LDS round-trip).
// PV: D[d][q] = mfma(A=V^T, B=P)  -> alpha rescale is lane-local.
// C/D map (m74/m101): col=lane&31, row=(reg&3)+8*(reg>>2)+4*(lane>>5).
// A/B k-map: k = 8*(lane>>5)+e (consistent A/B pair in QK; PV's P-frag built
// to match from the verified C/D key positions).
// ---------------------------------------------------------------------------
__global__ __launch_bounds__(256) void attn_mfma(
    const u16* __restrict__ Q, const u16* __restrict__ K,
    const u16* __restrict__ VT, u16* __restrict__ CTXhi,
    u16* __restrict__ CTXlo) {
  __shared__ u16 Ks[64][72];  // [key][d]  pad->144B rows
  __shared__ u16 Vs[64][72];  // [d][key]

  const int t = threadIdx.x;
  const int lane = t & 63;
  const int w = t >> 6;
  const int l31 = lane & 31;
  const int hsel = lane >> 5;  // 0/1
  const int qt = blockIdx.x, h = blockIdx.y, b = blockIdx.z;

  const size_t base = (size_t)(b * NHEADS + h) * SEQ * HSZ;
  const u16* Qg = Q + base;
  const u16* Kg = K + base;
  const u16* Vg = VT + base;  // [64][SEQ]
  const int q0 = qt * 256 + w * 64;

  // Q B-frags: [qsub][dstep], lane holds Q[q0+32*qsub+l31][16*ds+8*hsel+e]
  bf16x8 qf[2][4];
#pragma unroll
  for (int s = 0; s < 2; ++s)
#pragma unroll
    for (int ds = 0; ds < 4; ++ds)
      qf[s][ds] = *(const bf16x8*)&Qg[(size_t)(q0 + 32 * s + l31) * HSZ +
                                      16 * ds + 8 * hsel];

  f32x16 oacc[2][2];  // [qsub][dt]
#pragma unroll
  for (int s = 0; s < 2; ++s)
#pragma unroll
    for (int dt = 0; dt < 2; ++dt)
#pragma unroll
      for (int r = 0; r < 16; ++r) oacc[s][dt][r] = 0.0f;
  float m_[2] = {-INFINITY, -INFINITY};
  float l_[2] = {0.0f, 0.0f};

  const int srow = t >> 3;       // 0..31 staging row
  const int scol = (t & 7) * 8;  // 0..56

  for (int kt = 0; kt < SEQ / 64; ++kt) {
    __syncthreads();
#pragma unroll
    for (int p = 0; p < 2; ++p) {
      const int r = srow + 32 * p;
      *(uint4*)&Ks[r][scol] =
          *(const uint4*)&Kg[(size_t)(kt * 64 + r) * HSZ + scol];
      *(uint4*)&Vs[r][scol] =
          *(const uint4*)&Vg[(size_t)r * SEQ + (size_t)kt * 64 + scol];
    }
    __syncthreads();

#pragma unroll
    for (int ksub = 0; ksub < 2; ++ksub) {
      // K A-frags (shared across both q-subtiles)
      bf16x8 kf[4];
#pragma unroll
      for (int ds = 0; ds < 4; ++ds)
        kf[ds] = *(const bf16x8*)&Ks[32 * ksub + l31][16 * ds + 8 * hsel];
      // V^T A-frags [ks][dt]
      bf16x8 vf[2][2];
#pragma unroll
      for (int ks = 0; ks < 2; ++ks)
#pragma unroll
        for (int dt = 0; dt < 2; ++dt)
          vf[ks][dt] = *(const bf16x8*)&Vs[32 * dt + l31]
                                          [32 * ksub + 16 * ks + 8 * hsel];

#pragma unroll
      for (int qs = 0; qs < 2; ++qs) {
        // QK^T (swapped): D[key][q]
        f32x16 sacc;
#pragma unroll
        for (int r = 0; r < 16; ++r) sacc[r] = 0.0f;
#pragma unroll
        for (int ds = 0; ds < 4; ++ds)
          sacc = __builtin_amdgcn_mfma_f32_32x32x16_bf16(kf[ds], qf[qs][ds],
                                                         sacc, 0, 0, 0);

        // in-lane tile max over 16 keys + partner half
        float rm = sacc[0];
#pragma unroll
        for (int r = 1; r < 16; ++r) rm = fmaxf(rm, sacc[r]);
        rm = fmaxf(rm, __shfl_xor(rm, 32));

        // defer-max: rescale only when tile max grows past THR
        if (!__all(rm <= m_[qs] + 8.0f)) {
          const float mn = fmaxf(m_[qs], rm);
          const float al = __expf(m_[qs] - mn);
          m_[qs] = mn;
          l_[qs] *= al;
#pragma unroll
          for (int dt = 0; dt < 2; ++dt)
#pragma unroll
            for (int r = 0; r < 16; ++r) oacc[qs][dt][r] *= al;
        }

        // p = exp(s - m), row sum
        float p[16];
        float rs = 0.0f;
#pragma unroll
        for (int r = 0; r < 16; ++r) {
          p[r] = __expf(sacc[r] - m_[qs]);
          rs += p[r];
        }
        rs += __shfl_xor(rs, 32);
        l_[qs] += rs;

        // pack to bf16 pairs, then permlane-swap into PV B-frags
        unsigned int pk[8];
#pragma unroll
        for (int i = 0; i < 8; ++i)
          asm("v_cvt_pk_bf16_f32 %0, %1, %2"
              : "=v"(pk[i])
              : "v"(p[2 * i]), "v"(p[2 * i + 1]));
        asm("v_permlane32_swap_b32 %0, %1" : "+v"(pk[0]), "+v"(pk[2]));
        asm("v_permlane32_swap_b32 %0, %1" : "+v"(pk[1]), "+v"(pk[3]));
        asm("v_permlane32_swap_b32 %0, %1" : "+v"(pk[4]), "+v"(pk[6]));
        asm("v_permlane32_swap_b32 %0, %1" : "+v"(pk[5]), "+v"(pk[7]));
        const bf16x8 pf0 =
            __builtin_bit_cast(bf16x8, (u32x4){pk[0], pk[1], pk[2], pk[3]});
        const bf16x8 pf1 =
            __builtin_bit_cast(bf16x8, (u32x4){pk[4], pk[5], pk[6], pk[7]});

        // PV (swapped): D[d][q] += V^T * P
#pragma unroll
        for (int dt = 0; dt < 2; ++dt) {
          oacc[qs][dt] = __builtin_amdgcn_mfma_f32_32x32x16_bf16(
              vf[0][dt], pf0, oacc[qs][dt], 0, 0, 0);
          oacc[qs][dt] = __builtin_amdgcn_mfma_f32_32x32x16_bf16(
              vf[1][dt], pf1, oacc[qs][dt], 0, 0, 0);
        }
      }
    }
  }

  // epilogue: normalize, emit ctx hi/lo planes [B,S,H]
#pragma unroll
  for (int qs = 0; qs < 2; ++qs) {
    const float inv = 1.0f / l_[qs];
    const int q = q0 + 32 * qs + l31;
    u16* baseHi = CTXhi + ((size_t)b * SEQ + q) * H + h * HSZ;
    u16* baseLo = CTXlo + ((size_t)b * SEQ + q) * H + h * HSZ;
#pragma unroll
    for (int dt = 0; dt < 2; ++dt)
#pragma unroll
      for (int rg = 0; rg < 4; ++rg) {
        const int d0 = 32 * dt + 8 * rg + 4 * hsel;
        ushort4 vh, vl;
        float v0 = oacc[qs][dt][4 * rg + 0] * inv;
        float v1 = oacc[qs][dt][4 * rg + 1] * inv;
        float v2 = oacc[qs][dt][4 * rg + 2] * inv;
        float v3 = oacc[qs][dt][4 * rg + 3] * inv;
        vh.x = f2bf(v0); vl.x = f2bf(v0 - bf2f(vh.x));
        vh.y = f2bf(v1); vl.y = f2bf(v1 - bf2f(vh.y));
        vh.z = f2bf(v2); vl.z = f2bf(v2 - bf2f(vh.z));
        vh.w = f2bf(v3); vl.w = f2bf(v3 - bf2f(vh.w));
        *(ushort4*)&baseHi[d0] = vh;
        *(ushort4*)&baseLo[d0] = vl;
      }
  }
}

// ---------------------------------------------------------------------------
extern "C" void kernel_launch(void* const* d_in, const int* in_sizes, int n_in,
                              void* d_out, int out_size, void* d_ws,
                              size_t ws_size, hipStream_t stream) {
  const float* x = (const float*)d_in[0];
  const float* Wq = (const float*)d_in[1];
  const float* bq = (const float*)d_in[2];
  const float* Wk = (const float*)d_in[3];
  const float* bk = (const float*)d_in[4];
  const float* Wv = (const float*)d_in[5];
  const float* bv = (const float*)d_in[6];
  const float* Wo = (const float*)d_in[7];
  const float* bo = (const float*)d_in[8];

  const size_t PER = (size_t)4 * NHEADS * SEQ * HSZ;  // 8388608
  const size_t WSZ = (size_t)H * H;                   // 1048576
  u16* Qb = (u16*)d_ws;
  u16* Kb = Qb + PER;
  u16* Vb = Kb + PER;
  u16* VTb = Vb + PER;
  u16* CTXhi = VTb + PER;
  u16* CTXlo = CTXhi + PER;
  u16* Xb = CTXlo + PER;
  u16* Wqb = Xb + PER;
  u16* Wkb = Wqb + WSZ;
  u16* Wvb = Wkb + WSZ;
  u16* Wohi = Wvb + WSZ;
  u16* Wolo = Wohi + WSZ;

  cast_x<<<2048, 256, 0, stream>>>(x, Xb);
  cast_w<<<dim3(256, 4), 256, 0, stream>>>(Wq, Wk, Wv, Wo, Wqb, Wkb, Wvb,
                                           Wohi, Wolo);

  qkv_mfma<<<dim3(H / 128, NROWS / 128, 3), 256, 0, stream>>>(
      Xb, Wqb, Wkb, Wvb, bq, bk, bv, Qb, Kb, Vb);

  transpose_v<<<dim3(SEQ / 64, NHEADS, 4), 256, 0, stream>>>(Vb, VTb);

  attn_mfma<<<dim3(SEQ / 256, NHEADS, 4), 256, 0, stream>>>(Qb, Kb, VTb,
                                                            CTXhi, CTXlo);

  out_mfma<<<dim3(H / 128, NROWS / 128), 256, 0, stream>>>(
      CTXhi, CTXlo, Wohi, Wolo, bo, (float*)d_out);
}